// Round 6
// baseline (273.382 us; speedup 1.0000x reference)
//
#include <hip/hip_runtime.h>
#include <hip/hip_cooperative_groups.h>
#include <cstddef>

namespace cg = cooperative_groups;

#define T_LEN 4096
#define BATCH 4
#define HID   1024
#define NS    16
#define ROWS  (BATCH*T_LEN)   // 16384
#define CHUNK 32
#define NCH   (T_LEN/CHUNK)   // 128
#define GRID_B (ROWS/CHUNK)   // 512

// workspace float offsets
#define OFF_AD   0        // A_d [16][16]
#define OFF_P    1024     // P_k = A_d^k, k=1..32  [32][16][16]
#define OFF_BDH  32768    // B_d bf16 [16][1024] (2B elems)
#define OFF_LEND 49152    // chunk-end local states [4][128][16]

typedef __bf16 v8bf  __attribute__((ext_vector_type(8)));
typedef float  f32x4 __attribute__((ext_vector_type(4)));

union SharedU {
    struct {                       // setup phase (block 0 only)
        float red[256], Ms[256], term[256], E[256], G[256];
        float Pl[32*256];          // 32 KB
    } s;
    struct {                       // main phases (all blocks)
        float red[4*272];          // per-wave MFMA tiles, padded
        float us[32*20];           // chunk states, padded stride 20
        float le[NCH*16];          // staged chunk-ends for carry
        float cin[16];
    } m;
};

__global__ __launch_bounds__(256, 4) void mega_kernel(
        const float* __restrict__ x, const float* __restrict__ state,
        const float* __restrict__ A, const float* __restrict__ B,
        const float* __restrict__ C, const float* __restrict__ log_dt,
        float* __restrict__ ws, float* __restrict__ out) {
    __shared__ SharedU sh;
    const int tid = threadIdx.x;
    const int bid = blockIdx.x;
    cg::grid_group grid = cg::this_grid();

    // ============ phase S: setup + Bd (block 0 only) ============
    if (bid == 0) {
        // dt = mean(exp(log_dt))
        float s = 0.f;
        for (int i = tid; i < HID; i += 256) s += expf(log_dt[i]);
        sh.s.red[tid] = s;
        __syncthreads();
        for (int w2 = 128; w2 > 0; w2 >>= 1) {
            if (tid < w2) sh.s.red[tid] += sh.s.red[tid + w2];
            __syncthreads();
        }
        const float dt = sh.s.red[0] * (1.f/1024.f);

        const int r = tid >> 4, c = tid & 15;
        const float ident = (r == c) ? 1.f : 0.f;
        sh.s.Ms[tid]   = A[tid] * (dt * (1.f/64.f));
        sh.s.term[tid] = ident;
        sh.s.E[tid]    = ident;    // expm accumulator
        sh.s.G[tid]    = ident;    // phi1 accumulator
        __syncthreads();
        // Taylor 12: term_i = Ms^i/i!; E += term; G += term/(i+1)
        for (int i = 1; i <= 12; ++i) {
            float v = 0.f;
            #pragma unroll
            for (int m = 0; m < NS; ++m) v += sh.s.term[r*16+m] * sh.s.Ms[m*16+c];
            v /= (float)i;
            __syncthreads();
            sh.s.term[tid] = v;
            sh.s.E[tid] += v;
            sh.s.G[tid] += v * (1.f/(float)(i+1));
            __syncthreads();
        }
        // 6 doublings: G <- 0.5*G*(E+I); E <- E*E
        for (int d = 0; d < 6; ++d) {
            float ge = 0.f, ee = 0.f;
            #pragma unroll
            for (int m = 0; m < NS; ++m) {
                ge += sh.s.G[r*16+m] * (sh.s.E[m*16+c] + ((m==c)?1.f:0.f));
                ee += sh.s.E[r*16+m] * sh.s.E[m*16+c];
            }
            __syncthreads();
            sh.s.G[tid] = 0.5f * ge;
            sh.s.E[tid] = ee;
            __syncthreads();
        }
        ws[OFF_AD + tid] = sh.s.E[tid];          // A_d
        sh.s.Pl[tid] = sh.s.E[tid];              // P_1
        sh.s.red[tid] = dt * sh.s.G[tid];        // X = dt*phi1, kept in LDS
        __syncthreads();
        // powers by doubling up to P_32
        for (int pm = 1; pm < 32; pm <<= 1) {
            for (int idx = tid; idx < pm*256; idx += 256) {
                const int j = idx >> 8, e = idx & 255, rr = e >> 4, cc = e & 15;
                float v = 0.f;
                #pragma unroll
                for (int m = 0; m < NS; ++m)
                    v += sh.s.Pl[j*256 + rr*16 + m] * sh.s.Pl[(pm-1)*256 + m*16 + cc];
                sh.s.Pl[(pm + j)*256 + e] = v;
            }
            __syncthreads();
        }
        for (int i = tid*4; i < 32*256; i += 1024)
            *(float4*)(ws + OFF_P + i) = *(const float4*)(&sh.s.Pl[i]);
        // Bd bf16: bdh[n][h] = sum_m X[n][m] * B[m][h]
        __bf16* bdh = (__bf16*)(ws + OFF_BDH);
        for (int idx = tid; idx < NS*HID; idx += 256) {
            const int n = idx >> 10, h = idx & 1023;
            float a = 0.f;
            #pragma unroll
            for (int m = 0; m < NS; ++m) a += sh.s.red[n*16+m] * B[m*HID + h];
            bdh[n*HID + h] = (__bf16)a;
        }
    }
    __threadfence();
    grid.sync();

    // ============ phase A: u = x @ Bd^T via MFMA + local scan ============
    const int w    = tid >> 6;
    const int lane = tid & 63;
    const int row0 = bid * 32;
    const int rhalf = w & 1;          // 16-row half
    const int ks    = w >> 1;         // 512-wide k slice
    const int lr  = lane & 15;
    const int lkq = lane >> 4;
    const int lk  = lkq * 8;
    const int b   = bid >> 7;         // batch
    const int cch = bid & (NCH-1);    // chunk id within batch

    {
        const float*  xp = x + (size_t)(row0 + rhalf*16 + lr)*HID + ks*512 + lk;
        const __bf16* bp = (const __bf16*)(ws + OFF_BDH) + (size_t)lr*HID + ks*512 + lk;

        f32x4 acc = {0.f, 0.f, 0.f, 0.f};
        float4 xg[2][4][2]; v8bf bg[2][4];
        #pragma unroll
        for (int i = 0; i < 4; ++i) {
            xg[0][i][0] = *(const float4*)(xp + i*32);
            xg[0][i][1] = *(const float4*)(xp + i*32 + 4);
            bg[0][i]    = *(const v8bf*)(bp + i*32);
        }
        #pragma unroll
        for (int g = 0; g < 4; ++g) {
            const int cur = g & 1, nxt = cur ^ 1;
            if (g < 3) {
                const int off = (g+1)*128;
                #pragma unroll
                for (int i = 0; i < 4; ++i) {
                    xg[nxt][i][0] = *(const float4*)(xp + off + i*32);
                    xg[nxt][i][1] = *(const float4*)(xp + off + i*32 + 4);
                    bg[nxt][i]    = *(const v8bf*)(bp + off + i*32);
                }
            }
            #pragma unroll
            for (int i = 0; i < 4; ++i) {
                v8bf a;
                a[0]=(__bf16)xg[cur][i][0].x; a[1]=(__bf16)xg[cur][i][0].y;
                a[2]=(__bf16)xg[cur][i][0].z; a[3]=(__bf16)xg[cur][i][0].w;
                a[4]=(__bf16)xg[cur][i][1].x; a[5]=(__bf16)xg[cur][i][1].y;
                a[6]=(__bf16)xg[cur][i][1].z; a[7]=(__bf16)xg[cur][i][1].w;
                acc = __builtin_amdgcn_mfma_f32_16x16x32_bf16(a, bg[cur][i], acc, 0, 0, 0);
            }
        }
        // stash per-wave 16x16 tile (D: row=(lane>>4)*4+reg, col=lane&15)
        #pragma unroll
        for (int r4 = 0; r4 < 4; ++r4)
            sh.m.red[w*272 + lkq*68 + r4*16 + lr] = acc[r4];
    }
    __syncthreads();
    // combine 2 k-slices -> us (padded stride 20)
    for (int e = tid; e < 512; e += 256) {
        const int rowl = e >> 4, n = e & 15;
        const int rh = rowl >> 4, rl = rowl & 15;
        sh.m.us[rowl*20 + n] =
            sh.m.red[ rh   *272 + (rl>>2)*68 + (rl&3)*16 + n] +
            sh.m.red[(rh+2)*272 + (rl>>2)*68 + (rl&3)*16 + n];
    }
    __syncthreads();
    // local scan over 32 steps (wave 0, m-split 4-way)
    if (tid < 64) {
        const int n = tid & 15, mg = tid >> 4;
        const float a0 = ws[OFF_AD + (mg*4+0)*16 + n];
        const float a1 = ws[OFF_AD + (mg*4+1)*16 + n];
        const float a2 = ws[OFF_AD + (mg*4+2)*16 + n];
        const float a3 = ws[OFF_AD + (mg*4+3)*16 + n];
        float v = 0.f;
        for (int t = 0; t < CHUNK; ++t) {
            const float u0 = sh.m.us[t*20 + n];
            float q = __shfl(v, mg*4+0, 16)*a0 + __shfl(v, mg*4+1, 16)*a1
                    + __shfl(v, mg*4+2, 16)*a2 + __shfl(v, mg*4+3, 16)*a3;
            q += __shfl_xor(q, 16);
            q += __shfl_xor(q, 32);
            v = u0 + q;
            if (mg == 0) sh.m.us[t*20 + n] = v;
        }
        if (mg == 0) ws[OFF_LEND + (b*NCH + cch)*16 + n] = v;
    }
    __threadfence();
    grid.sync();

    // ============ phase B: per-block carry-in (redundant scan) ============
    for (int i = tid; i < cch*16; i += 256)
        sh.m.le[i] = ws[OFF_LEND + b*NCH*16 + i];
    __syncthreads();
    if (tid < 64) {
        const int n = tid & 15, mg = tid >> 4;
        const float p0 = ws[OFF_P + 31*256 + (mg*4+0)*16 + n];   // P_32
        const float p1 = ws[OFF_P + 31*256 + (mg*4+1)*16 + n];
        const float p2 = ws[OFF_P + 31*256 + (mg*4+2)*16 + n];
        const float p3 = ws[OFF_P + 31*256 + (mg*4+3)*16 + n];
        float v = state[b*16 + n];
        for (int j = 0; j < cch; ++j) {
            float q = __shfl(v, mg*4+0, 16)*p0 + __shfl(v, mg*4+1, 16)*p1
                    + __shfl(v, mg*4+2, 16)*p2 + __shfl(v, mg*4+3, 16)*p3;
            q += __shfl_xor(q, 16);
            q += __shfl_xor(q, 32);
            v = sh.m.le[j*16 + n] + q;
        }
        if (mg == 0) sh.m.cin[n] = v;
        if (cch == NCH-1) {   // final state = own_lend + P_32 * cin
            float q = __shfl(v, mg*4+0, 16)*p0 + __shfl(v, mg*4+1, 16)*p1
                    + __shfl(v, mg*4+2, 16)*p2 + __shfl(v, mg*4+3, 16)*p3;
            q += __shfl_xor(q, 16);
            q += __shfl_xor(q, 32);
            if (mg == 0) out[(size_t)ROWS*HID + b*16 + n] = sh.m.us[31*20 + n] + q;
        }
    }
    __syncthreads();

    // ============ phase C: corrected states (in-place in us) ============
    if (tid < 128) {
        const int j = tid >> 2, n4 = (tid & 3)*4;
        float4 ls = *(const float4*)(&sh.m.us[j*20 + n4]);
        const float* P = ws + OFF_P + j*256 + n4;    // P_{j+1}
        float cx=0.f, cy=0.f, cz=0.f, cw=0.f;
        #pragma unroll
        for (int m = 0; m < NS; ++m) {
            const float cm = sh.m.cin[m];
            float4 pv = *(const float4*)(P + m*16);
            cx += cm*pv.x; cy += cm*pv.y; cz += cm*pv.z; cw += cm*pv.w;
        }
        *(float4*)(&sh.m.us[j*20 + n4]) = make_float4(ls.x+cx, ls.y+cy, ls.z+cz, ls.w+cw);
    }
    __syncthreads();

    // ============ phase E: out = states @ C^T via MFMA ============
    const int nh = w >> 1;
    v8bf afr = {};
    if (lk < 16) {
        float4 s0 = *(const float4*)(&sh.m.us[(rhalf*16 + lr)*20 + lk]);
        float4 s1 = *(const float4*)(&sh.m.us[(rhalf*16 + lr)*20 + lk + 4]);
        afr[0]=(__bf16)s0.x; afr[1]=(__bf16)s0.y; afr[2]=(__bf16)s0.z; afr[3]=(__bf16)s0.w;
        afr[4]=(__bf16)s1.x; afr[5]=(__bf16)s1.y; afr[6]=(__bf16)s1.z; afr[7]=(__bf16)s1.w;
    }
    const int orow = row0 + rhalf*16 + lkq*4;
    #pragma unroll 4
    for (int nt = 0; nt < 32; ++nt) {
        const int n0 = (nh*32 + nt)*16;
        v8bf bfr = {};
        if (lk < 16) {
            float4 c0 = *(const float4*)(C + (size_t)(n0 + lr)*16 + lk);
            float4 c1 = *(const float4*)(C + (size_t)(n0 + lr)*16 + lk + 4);
            bfr[0]=(__bf16)c0.x; bfr[1]=(__bf16)c0.y; bfr[2]=(__bf16)c0.z; bfr[3]=(__bf16)c0.w;
            bfr[4]=(__bf16)c1.x; bfr[5]=(__bf16)c1.y; bfr[6]=(__bf16)c1.z; bfr[7]=(__bf16)c1.w;
        }
        f32x4 acc2 = {0.f, 0.f, 0.f, 0.f};
        acc2 = __builtin_amdgcn_mfma_f32_16x16x32_bf16(afr, bfr, acc2, 0, 0, 0);
        #pragma unroll
        for (int rg = 0; rg < 4; ++rg)
            out[(size_t)(orow + rg)*HID + n0 + lr] = acc2[rg];
    }
}

extern "C" void kernel_launch(void* const* d_in, const int* in_sizes, int n_in,
                              void* d_out, int out_size, void* d_ws, size_t ws_size,
                              hipStream_t stream) {
    (void)in_sizes; (void)n_in; (void)out_size; (void)ws_size;
    const float* x      = (const float*)d_in[0];
    const float* state  = (const float*)d_in[1];
    const float* A      = (const float*)d_in[2];
    const float* B      = (const float*)d_in[3];
    const float* C      = (const float*)d_in[4];
    const float* log_dt = (const float*)d_in[5];
    float* out = (float*)d_out;
    float* ws  = (float*)d_ws;

    void* args[8] = { (void*)&x, (void*)&state, (void*)&A, (void*)&B,
                      (void*)&C, (void*)&log_dt, (void*)&ws, (void*)&out };
    hipLaunchCooperativeKernel((void*)mega_kernel, dim3(GRID_B), dim3(256),
                               args, 0, stream);
}

// Round 7
// 69.878 us; speedup vs baseline: 3.9123x; 3.9123x over previous
//
#include <hip/hip_runtime.h>
#include <cstddef>

#define T_LEN 4096
#define BATCH 4
#define HID   1024
#define NS    16
#define ROWS  (BATCH*T_LEN)   // 16384
#define CHUNK 32
#define NCH   (T_LEN/CHUNK)   // 128

// workspace float offsets
#define OFF_AD   0        // A_d [16][16]
#define OFF_P    1024     // P_j = A_d^(j+1), j=0..31   [32][16][16]
#define OFF_BDH  16384    // B_d bf16 [16][1024] (8192 floats)
#define OFF_Q    32768    // Q_k = (A_d^32)^k, k=0..127 [128][16][16]
#define OFF_U    65536    // local states [16384][16]
#define OFF_LEND 327680   // chunk-end local states [4][128][16]

typedef __bf16 v8bf  __attribute__((ext_vector_type(8)));
typedef float  f32x4 __attribute__((ext_vector_type(4)));

// ---------- setup_bd: every block computes dt,expm,phi1 -> Bd slice;
//            block 0 additionally writes A_d, P table, Q table ----------
__global__ __launch_bounds__(256) void setup_bd_kernel(const float* __restrict__ A,
                                                       const float* __restrict__ B,
                                                       const float* __restrict__ log_dt,
                                                       float* __restrict__ ws) {
    __shared__ float red[256], Ms[256], term[256], E[256], G[256];
    __shared__ float Pl[32*256];   // 32 KB
    __shared__ float Ql[64*256];   // 64 KB
    const int tid = threadIdx.x;
    const int bid = blockIdx.x;

    // dt = mean(exp(log_dt))
    float s = 0.f;
    for (int i = tid; i < HID; i += 256) s += expf(log_dt[i]);
    red[tid] = s;
    __syncthreads();
    for (int w2 = 128; w2 > 0; w2 >>= 1) {
        if (tid < w2) red[tid] += red[tid + w2];
        __syncthreads();
    }
    const float dt = red[0] * (1.f/1024.f);

    const int r = tid >> 4, c = tid & 15;
    const float ident = (r == c) ? 1.f : 0.f;
    Ms[tid]   = A[tid] * (dt * (1.f/64.f));
    term[tid] = ident;
    E[tid]    = ident;   // expm accumulator
    G[tid]    = ident;   // phi1 accumulator
    __syncthreads();
    // Taylor 12: term_i = Ms^i/i!; E += term; G += term/(i+1)
    for (int i = 1; i <= 12; ++i) {
        float v = 0.f;
        #pragma unroll
        for (int m = 0; m < NS; ++m) v += term[r*16+m] * Ms[m*16+c];
        v /= (float)i;
        __syncthreads();
        term[tid] = v;
        E[tid] += v;
        G[tid] += v * (1.f/(float)(i+1));
        __syncthreads();
    }
    // 6 doublings: G <- 0.5*G*(E+I); E <- E*E
    for (int d = 0; d < 6; ++d) {
        float ge = 0.f, ee = 0.f;
        #pragma unroll
        for (int m = 0; m < NS; ++m) {
            ge += G[r*16+m] * (E[m*16+c] + ((m==c)?1.f:0.f));
            ee += E[r*16+m] * E[m*16+c];
        }
        __syncthreads();
        G[tid] = 0.5f * ge;
        E[tid] = ee;
        __syncthreads();
    }
    red[tid] = dt * G[tid];   // X = dt*phi1
    __syncthreads();

    // Bd slice: this block's 256 elements
    {
        const int idx = bid * 256 + tid;
        const int n = idx >> 10, h = idx & 1023;
        float a = 0.f;
        #pragma unroll
        for (int m = 0; m < NS; ++m) a += red[n*16+m] * B[m*HID + h];
        __bf16* bdh = (__bf16*)(ws + OFF_BDH);
        bdh[n*HID + h] = (__bf16)a;
    }

    if (bid != 0) return;

    // ---- block 0: A_d, P table (A_d^1..32), Q table ((A_d^32)^0..127) ----
    ws[OFF_AD + tid] = E[tid];
    Pl[tid] = E[tid];          // P_1
    __syncthreads();
    for (int pm = 1; pm < 32; pm <<= 1) {
        for (int idx = tid; idx < pm*256; idx += 256) {
            const int j = idx >> 8, e = idx & 255, rr = e >> 4, cc = e & 15;
            float v = 0.f;
            #pragma unroll
            for (int m = 0; m < NS; ++m)
                v += Pl[j*256 + rr*16 + m] * Pl[(pm-1)*256 + m*16 + cc];
            Pl[(pm + j)*256 + e] = v;
        }
        __syncthreads();
    }
    for (int i = tid*4; i < 32*256; i += 1024)
        *(float4*)(ws + OFF_P + i) = *(const float4*)(&Pl[i]);

    // Q_0 = I, Q_1 = P_32
    Ql[tid] = Pl[31*256 + tid];
    ws[OFF_Q + tid]       = ident;
    ws[OFF_Q + 256 + tid] = Ql[tid];
    __syncthreads();
    for (int pm = 1; pm < 128; pm <<= 1) {
        const int jmax = (pm < 127 - pm) ? pm : (127 - pm);
        for (int idx = tid; idx < jmax*256; idx += 256) {
            const int j1 = (idx >> 8) + 1, e = idx & 255, rr = e >> 4, cc = e & 15;
            float v = 0.f;
            #pragma unroll
            for (int m = 0; m < NS; ++m)
                v += Ql[(j1-1)*256 + rr*16 + m] * Ql[(pm-1)*256 + m*16 + cc];
            const int k = pm + j1;
            if (k <= 64) Ql[(k-1)*256 + e] = v;
            ws[OFF_Q + k*256 + e] = v;
        }
        __syncthreads();
    }
}

// ---------- K1: u = x @ B_d^T via MFMA + local chunk scan ----------
// 512 thr = 8 waves: rhalf = w&1 (16-row half), ks = w>>1 (K/4 = 256 slice)
__global__ __launch_bounds__(512, 4) void k1_kernel(const float* __restrict__ x,
                                                    float* __restrict__ ws) {
    __shared__ __align__(16) float red[8*256];     // per-wave partial tiles, 8 KB
    __shared__ __align__(16) float us[32*16];      // u -> local states, 2 KB
    const int tid  = threadIdx.x;
    const int w    = tid >> 6;
    const int lane = tid & 63;
    const int row0 = blockIdx.x * 32;
    const int rhalf = w & 1;
    const int ks    = w >> 1;
    const int lr = lane & 15;
    const int lk = (lane >> 4) * 8;

    const float*  xp  = x + (size_t)(row0 + rhalf*16 + lr)*HID + ks*256 + lk;
    const __bf16* bp  = (const __bf16*)(ws + OFF_BDH) + (size_t)lr*HID + ks*256 + lk;

    float4 xv0[4][2]; v8bf bv0[4];
    #pragma unroll
    for (int i = 0; i < 4; ++i) {
        xv0[i][0] = *(const float4*)(xp + i*32);
        xv0[i][1] = *(const float4*)(xp + i*32 + 4);
        bv0[i]    = *(const v8bf*)(bp + i*32);
    }
    float4 xv1[4][2]; v8bf bv1[4];
    #pragma unroll
    for (int i = 0; i < 4; ++i) {
        xv1[i][0] = *(const float4*)(xp + 128 + i*32);
        xv1[i][1] = *(const float4*)(xp + 128 + i*32 + 4);
        bv1[i]    = *(const v8bf*)(bp + 128 + i*32);
    }

    f32x4 acc = {0.f, 0.f, 0.f, 0.f};
    #pragma unroll
    for (int i = 0; i < 4; ++i) {
        v8bf a;
        a[0]=(__bf16)xv0[i][0].x; a[1]=(__bf16)xv0[i][0].y; a[2]=(__bf16)xv0[i][0].z; a[3]=(__bf16)xv0[i][0].w;
        a[4]=(__bf16)xv0[i][1].x; a[5]=(__bf16)xv0[i][1].y; a[6]=(__bf16)xv0[i][1].z; a[7]=(__bf16)xv0[i][1].w;
        acc = __builtin_amdgcn_mfma_f32_16x16x32_bf16(a, bv0[i], acc, 0, 0, 0);
    }
    #pragma unroll
    for (int i = 0; i < 4; ++i) {
        v8bf a;
        a[0]=(__bf16)xv1[i][0].x; a[1]=(__bf16)xv1[i][0].y; a[2]=(__bf16)xv1[i][0].z; a[3]=(__bf16)xv1[i][0].w;
        a[4]=(__bf16)xv1[i][1].x; a[5]=(__bf16)xv1[i][1].y; a[6]=(__bf16)xv1[i][1].z; a[7]=(__bf16)xv1[i][1].w;
        acc = __builtin_amdgcn_mfma_f32_16x16x32_bf16(a, bv1[i], acc, 0, 0, 0);
    }

    #pragma unroll
    for (int rreg = 0; rreg < 4; ++rreg)
        red[w*256 + ((lane>>4)*4 + rreg)*16 + lr] = acc[rreg];
    __syncthreads();
    {
        const int rowl = tid >> 4, n = tid & 15;
        const int rh = rowl >> 4, rl = rowl & 15;
        float v = 0.f;
        #pragma unroll
        for (int kk = 0; kk < 4; ++kk)
            v += red[(rh + 2*kk)*256 + rl*16 + n];
        us[tid] = v;
    }
    __syncthreads();
    // local scan over 32 steps (wave 0, m-split 4-way)
    if (tid < 64) {
        const int n = tid & 15, mg = tid >> 4;
        const float a0 = ws[OFF_AD + (mg*4+0)*16 + n];
        const float a1 = ws[OFF_AD + (mg*4+1)*16 + n];
        const float a2 = ws[OFF_AD + (mg*4+2)*16 + n];
        const float a3 = ws[OFF_AD + (mg*4+3)*16 + n];
        float v = 0.f;
        for (int t = 0; t < CHUNK; ++t) {
            const float u0 = us[t*16 + n];
            float q = __shfl(v, mg*4+0, 16)*a0 + __shfl(v, mg*4+1, 16)*a1
                    + __shfl(v, mg*4+2, 16)*a2 + __shfl(v, mg*4+3, 16)*a3;
            q += __shfl_xor(q, 16);
            q += __shfl_xor(q, 32);
            v = u0 + q;
            if (mg == 0) us[t*16 + n] = v;
        }
        if (mg == 0) {
            const int b = row0 >> 12, cch = (row0 >> 5) & (NCH-1);
            ws[OFF_LEND + (b*NCH + cch)*16 + n] = v;
        }
    }
    __syncthreads();
    if (tid < 128) {
        const int j = tid >> 2, nq = (tid & 3)*4;
        *(float4*)(ws + OFF_U + (size_t)(row0 + j)*16 + nq) = *(const float4*)(&us[j*16 + nq]);
    }
}

// ---------- K2: cin via Q-table sum, correction, out = states @ C^T ----------
__global__ __launch_bounds__(256, 2) void k2_kernel(const float* __restrict__ C,
                                                    const float* __restrict__ state,
                                                    const float* __restrict__ ws,
                                                    float* __restrict__ out) {
    __shared__ __align__(16) float st[32*20];     // padded stride 20
    __shared__ float vec[(NCH+1)*16];             // lend_0..c-1, state0
    __shared__ float part[16][17];
    __shared__ float cin_s[16];
    const int tid = threadIdx.x;
    const int row0 = blockIdx.x * 32;
    const int b = row0 >> 12, cch = (row0 >> 5) & (NCH-1);

    // load local states
    if (tid < 128) {
        const int j = tid >> 2, n4 = (tid & 3)*4;
        *(float4*)(&st[j*20 + n4]) =
            *(const float4*)(ws + OFF_U + (size_t)(row0 + j)*16 + n4);
    }
    // stage preceding chunk-ends + initial state
    for (int i = tid; i < cch*16; i += 256)
        vec[i] = ws[OFF_LEND + b*NCH*16 + i];
    if (tid < 16) vec[cch*16 + tid] = state[b*16 + tid];
    __syncthreads();

    // cin = state0*Q_cch + sum_j lend_j * Q_{cch-1-j}
    {
        const int g = tid >> 4, n = tid & 15;
        float p = 0.f;
        for (int j = g; j <= cch; j += 16) {
            const int qidx = (j == cch) ? cch : (cch - 1 - j);
            const float* Q = ws + OFF_Q + qidx*256;
            float sv = 0.f;
            #pragma unroll
            for (int m = 0; m < NS; ++m) sv += vec[j*16 + m] * Q[m*16 + n];
            p += sv;
        }
        part[g][n] = p;
    }
    __syncthreads();
    for (int s2 = 8; s2 > 0; s2 >>= 1) {
        if ((tid >> 4) < s2) part[tid>>4][tid&15] += part[(tid>>4)+s2][tid&15];
        __syncthreads();
    }
    if (tid < 16) cin_s[tid] = part[0][tid];
    __syncthreads();

    // correction: st[j] += cin * P_{j+1}
    if (tid < 128) {
        const int j = tid >> 2, n4 = (tid & 3)*4;
        float4 ls = *(const float4*)(&st[j*20 + n4]);
        const float* P = ws + OFF_P + j*256 + n4;
        float cx=0.f, cy=0.f, cz=0.f, cw=0.f;
        #pragma unroll
        for (int m = 0; m < NS; ++m) {
            const float cm = cin_s[m];
            float4 pv = *(const float4*)(P + m*16);
            cx += cm*pv.x; cy += cm*pv.y; cz += cm*pv.z; cw += cm*pv.w;
        }
        *(float4*)(&st[j*20 + n4]) = make_float4(ls.x+cx, ls.y+cy, ls.z+cz, ls.w+cw);
    }
    __syncthreads();
    // final state = corrected last row of last chunk
    if (cch == NCH-1 && tid < 16)
        out[(size_t)ROWS*HID + b*16 + tid] = st[31*20 + tid];

    // out = states @ C^T via MFMA
    const int w = tid >> 6, lane = tid & 63;
    const int rhalf = w & 1, nh = w >> 1;
    const int lr = lane & 15;
    const int lkq = lane >> 4;
    const int lk = lkq * 8;   // 0,8 real; 16,24 -> zero

    v8bf afr = {};
    if (lk < 16) {
        float4 s0 = *(const float4*)(&st[(rhalf*16 + lr)*20 + lk]);
        float4 s1 = *(const float4*)(&st[(rhalf*16 + lr)*20 + lk + 4]);
        afr[0]=(__bf16)s0.x; afr[1]=(__bf16)s0.y; afr[2]=(__bf16)s0.z; afr[3]=(__bf16)s0.w;
        afr[4]=(__bf16)s1.x; afr[5]=(__bf16)s1.y; afr[6]=(__bf16)s1.z; afr[7]=(__bf16)s1.w;
    }
    const int orow = row0 + rhalf*16 + lkq*4;
    #pragma unroll 4
    for (int nt = 0; nt < 32; ++nt) {
        const int n0 = (nh*32 + nt)*16;
        v8bf bfr = {};
        if (lk < 16) {
            float4 c0 = *(const float4*)(C + (size_t)(n0 + lr)*16 + lk);
            float4 c1 = *(const float4*)(C + (size_t)(n0 + lr)*16 + lk + 4);
            bfr[0]=(__bf16)c0.x; bfr[1]=(__bf16)c0.y; bfr[2]=(__bf16)c0.z; bfr[3]=(__bf16)c0.w;
            bfr[4]=(__bf16)c1.x; bfr[5]=(__bf16)c1.y; bfr[6]=(__bf16)c1.z; bfr[7]=(__bf16)c1.w;
        }
        f32x4 acc2 = {0.f, 0.f, 0.f, 0.f};
        acc2 = __builtin_amdgcn_mfma_f32_16x16x32_bf16(afr, bfr, acc2, 0, 0, 0);
        #pragma unroll
        for (int rg = 0; rg < 4; ++rg)
            out[(size_t)(orow + rg)*HID + n0 + lr] = acc2[rg];
    }
}

extern "C" void kernel_launch(void* const* d_in, const int* in_sizes, int n_in,
                              void* d_out, int out_size, void* d_ws, size_t ws_size,
                              hipStream_t stream) {
    (void)in_sizes; (void)n_in; (void)out_size; (void)ws_size;
    const float* x      = (const float*)d_in[0];
    const float* state  = (const float*)d_in[1];
    const float* A      = (const float*)d_in[2];
    const float* B      = (const float*)d_in[3];
    const float* C      = (const float*)d_in[4];
    const float* log_dt = (const float*)d_in[5];
    float* out = (float*)d_out;
    float* ws  = (float*)d_ws;

    setup_bd_kernel<<<64, 256, 0, stream>>>(A, B, log_dt, ws);
    k1_kernel      <<<ROWS/32, 512, 0, stream>>>(x, ws);
    k2_kernel      <<<ROWS/32, 256, 0, stream>>>(C, state, ws, out);
}

// Round 8
// 56.757 us; speedup vs baseline: 4.8167x; 1.2312x over previous
//
#include <hip/hip_runtime.h>
#include <cstddef>

#define T_LEN 4096
#define BATCH 4
#define HID   1024
#define NS    16
#define ROWS  (BATCH*T_LEN)   // 16384
#define CHUNK 32
#define NCH   (T_LEN/CHUNK)   // 128

// workspace float offsets
#define OFF_AD   0        // A_d [16][16]
#define OFF_P    1024     // P_j = A_d^(j+1), j=0..31   [32][16][16]
#define OFF_BDH  16384    // B_d bf16 [16][1024] (8192 floats)
#define OFF_Q    32768    // Q_k = (A_d^32)^k, k=0..127 [128][16][16]
#define OFF_U    65536    // local states [16384][16]
#define OFF_LEND 327680   // chunk-end local states [4][128][16]

typedef __bf16 v8bf  __attribute__((ext_vector_type(8)));
typedef float  f32x4 __attribute__((ext_vector_type(4)));

// ---------- setup_bd: all blocks: dt, expm, phi1, Bd slice; table roles
//            split across blocks via binary powering ----------
__global__ __launch_bounds__(256) void setup_bd_kernel(const float* __restrict__ A,
                                                       const float* __restrict__ B,
                                                       const float* __restrict__ log_dt,
                                                       float* __restrict__ ws) {
    __shared__ float red[256], Ms[256], term[256], E[256], G[256];
    __shared__ float S2[6][256];   // A_d^(2^j), j=0..5
    __shared__ float T2[7][256];   // (A_d^32)^(2^j), j=0..6
    __shared__ float V0[256], V1[256];
    const int tid = threadIdx.x;
    const int bid = blockIdx.x;

    // dt = mean(exp(log_dt))
    float s = 0.f;
    for (int i = tid; i < HID; i += 256) s += expf(log_dt[i]);
    red[tid] = s;
    __syncthreads();
    for (int w2 = 128; w2 > 0; w2 >>= 1) {
        if (tid < w2) red[tid] += red[tid + w2];
        __syncthreads();
    }
    const float dt = red[0] * (1.f/1024.f);

    const int r = tid >> 4, c = tid & 15;
    const float ident = (r == c) ? 1.f : 0.f;
    Ms[tid]   = A[tid] * (dt * (1.f/64.f));
    term[tid] = ident;
    E[tid]    = ident;   // expm accumulator
    G[tid]    = ident;   // phi1 accumulator
    __syncthreads();
    // Taylor 12: term_i = Ms^i/i!; E += term; G += term/(i+1)
    for (int i = 1; i <= 12; ++i) {
        float v = 0.f;
        #pragma unroll
        for (int m = 0; m < NS; ++m) v += term[r*16+m] * Ms[m*16+c];
        v /= (float)i;
        __syncthreads();
        term[tid] = v;
        E[tid] += v;
        G[tid] += v * (1.f/(float)(i+1));
        __syncthreads();
    }
    // 6 doublings: G <- 0.5*G*(E+I); E <- E*E
    for (int d = 0; d < 6; ++d) {
        float ge = 0.f, ee = 0.f;
        #pragma unroll
        for (int m = 0; m < NS; ++m) {
            ge += G[r*16+m] * (E[m*16+c] + ((m==c)?1.f:0.f));
            ee += E[r*16+m] * E[m*16+c];
        }
        __syncthreads();
        G[tid] = 0.5f * ge;
        E[tid] = ee;
        __syncthreads();
    }
    red[tid] = dt * G[tid];   // X = dt*phi1
    __syncthreads();

    // Bd slice (bf16): this block's 256 of 16384 elements
    {
        const int idx = bid * 256 + tid;
        const int n = idx >> 10, h = idx & 1023;
        float a = 0.f;
        #pragma unroll
        for (int m = 0; m < NS; ++m) a += red[n*16+m] * B[m*HID + h];
        __bf16* bdh = (__bf16*)(ws + OFF_BDH);
        bdh[n*HID + h] = (__bf16)a;
    }

    // power-of-two chains (every block, cheap: 11 small matmuls)
    S2[0][tid] = E[tid];
    __syncthreads();
    for (int j = 1; j < 6; ++j) {
        float v = 0.f;
        #pragma unroll
        for (int m = 0; m < NS; ++m) v += S2[j-1][r*16+m] * S2[j-1][m*16+c];
        S2[j][tid] = v;
        __syncthreads();
    }
    T2[0][tid] = S2[5][tid];
    __syncthreads();
    for (int j = 1; j < 7; ++j) {
        float v = 0.f;
        #pragma unroll
        for (int m = 0; m < NS; ++m) v += T2[j-1][r*16+m] * T2[j-1][m*16+c];
        T2[j][tid] = v;
        __syncthreads();
    }

    if (bid == 0) ws[OFF_AD + tid] = E[tid];

    // P table: blocks 0..7 write P_{4b+1..4b+4} (A_d^1..32)
    if (bid < 8) {
        for (int v4 = 0; v4 < 4; ++v4) {
            const int j2 = 4*bid + v4 + 1;   // 1..32
            float* Vc = V0; float* Vn = V1;
            bool have = false;
            for (int bit = 0; bit < 6; ++bit) {
                if (!((j2 >> bit) & 1)) continue;
                if (!have) {
                    Vc[tid] = S2[bit][tid];
                    have = true;
                    __syncthreads();
                } else {
                    float v = 0.f;
                    #pragma unroll
                    for (int m = 0; m < NS; ++m) v += Vc[r*16+m] * S2[bit][m*16+c];
                    Vn[tid] = v;
                    __syncthreads();
                    float* t1 = Vc; Vc = Vn; Vn = t1;
                }
            }
            ws[OFF_P + (j2-1)*256 + tid] = Vc[tid];
            __syncthreads();
        }
    }

    // Q table: blocks 16..47 write Q_{4(b-16)..4(b-16)+3} ((A_d^32)^0..127)
    if (bid >= 16 && bid < 48) {
        for (int v4 = 0; v4 < 4; ++v4) {
            const int k = 4*(bid-16) + v4;   // 0..127
            float* Vc = V0; float* Vn = V1;
            bool have = false;
            for (int bit = 0; bit < 7; ++bit) {
                if (!((k >> bit) & 1)) continue;
                if (!have) {
                    Vc[tid] = T2[bit][tid];
                    have = true;
                    __syncthreads();
                } else {
                    float v = 0.f;
                    #pragma unroll
                    for (int m = 0; m < NS; ++m) v += Vc[r*16+m] * T2[bit][m*16+c];
                    Vn[tid] = v;
                    __syncthreads();
                    float* t1 = Vc; Vc = Vn; Vn = t1;
                }
            }
            ws[OFF_Q + k*256 + tid] = have ? Vc[tid] : ident;
            __syncthreads();
        }
    }
}

// ---------- K1: u = x @ B_d^T via MFMA, 2-phase LDS pipeline + local scan ----------
// 512 thr = 8 waves: rhalf = w&1, ksub = w>>1 (64-K sub-range per wave per slice)
// x staged in double-buffered swizzled LDS tiles of 32 rows x 256 K.
__global__ __launch_bounds__(512, 4) void k1_kernel(const float* __restrict__ x,
                                                    float* __restrict__ ws) {
    __shared__ __align__(16) float xs[2][32*256];  // 64 KB double buffer
    __shared__ __align__(16) float red[8*256];     // 8 KB
    __shared__ __align__(16) float us[32*16];      // 2 KB
    const int tid  = threadIdx.x;
    const int w    = tid >> 6;
    const int lane = tid & 63;
    const int row0 = blockIdx.x * 32;
    const int rhalf = w & 1;
    const int ksub  = w >> 1;
    const int lr = lane & 15;
    const int hi = lane >> 4;
    const int r  = rhalf*16 + lr;
    const int swz = (r & 7) << 4;

    char* lds0 = (char*)&xs[0][0];
    char* lds1 = (char*)&xs[1][0];
    // staging geometry: thread covers rows w*4+i, 16B at col lane*16 (linear load,
    // swizzled LDS write: byte ^= (row&7)<<4)
    int loff[4];
    const float* gp[4];
    #pragma unroll
    for (int i = 0; i < 4; ++i) {
        const int row = w*4 + i;
        loff[i] = row*1024 + ((lane*16) ^ ((row & 7) << 4));
        gp[i] = x + (size_t)(row0 + row)*HID + lane*4;
    }

    // prologue: stage slice 0
    {
        float4 stg[4];
        #pragma unroll
        for (int i = 0; i < 4; ++i) stg[i] = *(const float4*)(gp[i]);
        #pragma unroll
        for (int i = 0; i < 4; ++i) *(float4*)(lds0 + loff[i]) = stg[i];
    }
    __syncthreads();

    f32x4 acc = {0.f, 0.f, 0.f, 0.f};
    const __bf16* bp = (const __bf16*)(ws + OFF_BDH) + (size_t)lr*HID + hi*8;

    for (int s4 = 0; s4 < 4; ++s4) {
        float4 stg[4];
        if (s4 < 3) {
            #pragma unroll
            for (int i = 0; i < 4; ++i)
                stg[i] = *(const float4*)(gp[i] + (s4+1)*256);
        }
        const char* base = (s4 & 1) ? lds1 : lds0;
        #pragma unroll
        for (int kk2 = 0; kk2 < 2; ++kk2) {
            const int kk = ksub*2 + kk2;
            const int colb = kk*128 + hi*32;
            float4 a0 = *(const float4*)(base + r*1024 + (colb ^ swz));
            float4 a1 = *(const float4*)(base + r*1024 + ((colb + 16) ^ swz));
            v8bf a;
            a[0]=(__bf16)a0.x; a[1]=(__bf16)a0.y; a[2]=(__bf16)a0.z; a[3]=(__bf16)a0.w;
            a[4]=(__bf16)a1.x; a[5]=(__bf16)a1.y; a[6]=(__bf16)a1.z; a[7]=(__bf16)a1.w;
            v8bf b = *(const v8bf*)(bp + s4*256 + kk*32);
            acc = __builtin_amdgcn_mfma_f32_16x16x32_bf16(a, b, acc, 0, 0, 0);
        }
        if (s4 < 3) {
            char* dst = (s4 & 1) ? lds0 : lds1;
            #pragma unroll
            for (int i = 0; i < 4; ++i) *(float4*)(dst + loff[i]) = stg[i];
        }
        __syncthreads();
    }

    // stash per-wave 16x16 tile (D: row=(lane>>4)*4+reg, col=lane&15)
    #pragma unroll
    for (int rreg = 0; rreg < 4; ++rreg)
        red[w*256 + (hi*4 + rreg)*16 + lr] = acc[rreg];
    __syncthreads();
    // combine 4 k-slices (wave-tile for (rh,ks) = red[(2ks+rh)*256])
    {
        const int rowl = tid >> 4, n = tid & 15;
        const int rh = rowl >> 4, rl = rowl & 15;
        float v = 0.f;
        #pragma unroll
        for (int kk = 0; kk < 4; ++kk)
            v += red[(rh + 2*kk)*256 + rl*16 + n];
        us[tid] = v;
    }
    __syncthreads();
    // local scan over 32 steps (wave 0, m-split 4-way)
    if (tid < 64) {
        const int n = tid & 15, mg = tid >> 4;
        const float a0 = ws[OFF_AD + (mg*4+0)*16 + n];
        const float a1 = ws[OFF_AD + (mg*4+1)*16 + n];
        const float a2 = ws[OFF_AD + (mg*4+2)*16 + n];
        const float a3 = ws[OFF_AD + (mg*4+3)*16 + n];
        float v = 0.f;
        for (int t = 0; t < CHUNK; ++t) {
            const float u0 = us[t*16 + n];
            float q = __shfl(v, mg*4+0, 16)*a0 + __shfl(v, mg*4+1, 16)*a1
                    + __shfl(v, mg*4+2, 16)*a2 + __shfl(v, mg*4+3, 16)*a3;
            q += __shfl_xor(q, 16);
            q += __shfl_xor(q, 32);
            v = u0 + q;
            if (mg == 0) us[t*16 + n] = v;
        }
        if (mg == 0) {
            const int b = row0 >> 12, cch = (row0 >> 5) & (NCH-1);
            ws[OFF_LEND + (b*NCH + cch)*16 + n] = v;
        }
    }
    __syncthreads();
    if (tid < 128) {
        const int j = tid >> 2, nq = (tid & 3)*4;
        *(float4*)(ws + OFF_U + (size_t)(row0 + j)*16 + nq) = *(const float4*)(&us[j*16 + nq]);
    }
}

// ---------- K2: cin via Q-table sum, correction, out = states @ C^T ----------
__global__ __launch_bounds__(256, 2) void k2_kernel(const float* __restrict__ C,
                                                    const float* __restrict__ state,
                                                    const float* __restrict__ ws,
                                                    float* __restrict__ out) {
    __shared__ __align__(16) float st[32*20];     // padded stride 20
    __shared__ float vec[(NCH+1)*16];             // lend_0..c-1, state0
    __shared__ float part[16][17];
    __shared__ float cin_s[16];
    const int tid = threadIdx.x;
    const int row0 = blockIdx.x * 32;
    const int b = row0 >> 12, cch = (row0 >> 5) & (NCH-1);

    // load local states
    if (tid < 128) {
        const int j = tid >> 2, n4 = (tid & 3)*4;
        *(float4*)(&st[j*20 + n4]) =
            *(const float4*)(ws + OFF_U + (size_t)(row0 + j)*16 + n4);
    }
    // stage preceding chunk-ends + initial state
    for (int i = tid; i < cch*16; i += 256)
        vec[i] = ws[OFF_LEND + b*NCH*16 + i];
    if (tid < 16) vec[cch*16 + tid] = state[b*16 + tid];
    __syncthreads();

    // cin = state0*Q_cch + sum_j lend_j * Q_{cch-1-j}
    {
        const int g = tid >> 4, n = tid & 15;
        float p = 0.f;
        for (int j = g; j <= cch; j += 16) {
            const int qidx = (j == cch) ? cch : (cch - 1 - j);
            const float* Q = ws + OFF_Q + qidx*256;
            float sv = 0.f;
            #pragma unroll
            for (int m = 0; m < NS; ++m) sv += vec[j*16 + m] * Q[m*16 + n];
            p += sv;
        }
        part[g][n] = p;
    }
    __syncthreads();
    for (int s2 = 8; s2 > 0; s2 >>= 1) {
        if ((tid >> 4) < s2) part[tid>>4][tid&15] += part[(tid>>4)+s2][tid&15];
        __syncthreads();
    }
    if (tid < 16) cin_s[tid] = part[0][tid];
    __syncthreads();

    // correction: st[j] += cin * P_{j+1}
    if (tid < 128) {
        const int j = tid >> 2, n4 = (tid & 3)*4;
        float4 ls = *(const float4*)(&st[j*20 + n4]);
        const float* P = ws + OFF_P + j*256 + n4;
        float cx=0.f, cy=0.f, cz=0.f, cw=0.f;
        #pragma unroll
        for (int m = 0; m < NS; ++m) {
            const float cm = cin_s[m];
            float4 pv = *(const float4*)(P + m*16);
            cx += cm*pv.x; cy += cm*pv.y; cz += cm*pv.z; cw += cm*pv.w;
        }
        *(float4*)(&st[j*20 + n4]) = make_float4(ls.x+cx, ls.y+cy, ls.z+cz, ls.w+cw);
    }
    __syncthreads();
    // final state = corrected last row of last chunk
    if (cch == NCH-1 && tid < 16)
        out[(size_t)ROWS*HID + b*16 + tid] = st[31*20 + tid];

    // out = states @ C^T via MFMA
    const int w = tid >> 6, lane = tid & 63;
    const int rhalf = w & 1, nh = w >> 1;
    const int lr = lane & 15;
    const int lkq = lane >> 4;
    const int lk = lkq * 8;   // 0,8 real; 16,24 -> zero

    v8bf afr = {};
    if (lk < 16) {
        float4 s0 = *(const float4*)(&st[(rhalf*16 + lr)*20 + lk]);
        float4 s1 = *(const float4*)(&st[(rhalf*16 + lr)*20 + lk + 4]);
        afr[0]=(__bf16)s0.x; afr[1]=(__bf16)s0.y; afr[2]=(__bf16)s0.z; afr[3]=(__bf16)s0.w;
        afr[4]=(__bf16)s1.x; afr[5]=(__bf16)s1.y; afr[6]=(__bf16)s1.z; afr[7]=(__bf16)s1.w;
    }
    const int orow = row0 + rhalf*16 + lkq*4;
    #pragma unroll 4
    for (int nt = 0; nt < 32; ++nt) {
        const int n0 = (nh*32 + nt)*16;
        v8bf bfr = {};
        if (lk < 16) {
            float4 c0 = *(const float4*)(C + (size_t)(n0 + lr)*16 + lk);
            float4 c1 = *(const float4*)(C + (size_t)(n0 + lr)*16 + lk + 4);
            bfr[0]=(__bf16)c0.x; bfr[1]=(__bf16)c0.y; bfr[2]=(__bf16)c0.z; bfr[3]=(__bf16)c0.w;
            bfr[4]=(__bf16)c1.x; bfr[5]=(__bf16)c1.y; bfr[6]=(__bf16)c1.z; bfr[7]=(__bf16)c1.w;
        }
        f32x4 acc2 = {0.f, 0.f, 0.f, 0.f};
        acc2 = __builtin_amdgcn_mfma_f32_16x16x32_bf16(afr, bfr, acc2, 0, 0, 0);
        #pragma unroll
        for (int rg = 0; rg < 4; ++rg)
            out[(size_t)(orow + rg)*HID + n0 + lr] = acc2[rg];
    }
}

extern "C" void kernel_launch(void* const* d_in, const int* in_sizes, int n_in,
                              void* d_out, int out_size, void* d_ws, size_t ws_size,
                              hipStream_t stream) {
    (void)in_sizes; (void)n_in; (void)out_size; (void)ws_size;
    const float* x      = (const float*)d_in[0];
    const float* state  = (const float*)d_in[1];
    const float* A      = (const float*)d_in[2];
    const float* B      = (const float*)d_in[3];
    const float* C      = (const float*)d_in[4];
    const float* log_dt = (const float*)d_in[5];
    float* out = (float*)d_out;
    float* ws  = (float*)d_ws;

    setup_bd_kernel<<<64, 256, 0, stream>>>(A, B, log_dt, ws);
    k1_kernel      <<<ROWS/32, 512, 0, stream>>>(x, ws);
    k2_kernel      <<<ROWS/32, 256, 0, stream>>>(C, state, ws, out);
}